// Round 1
// baseline (19.285 us; speedup 1.0000x reference)
//
#include <hip/hip_runtime.h>
#include <math.h>

#define DIM 4096
#define BATCH 8192
#define NTHREADS 1024

// One fused kernel, single block:
//  Phase 1: inclusive prefix scan over j=0..DIM-1 of 4 series
//           {g, g*log(j+1), g*log(lam), g*log1p(-lam)}  -> LDS float4[DIM]
//  Phase 2: per-beta gather of prefix at K-1, f64 accumulate 4 scalars
//  Phase 3: block reduce + scalar epilogue -> out[0]=rhs, out[1]=lhs
__global__ __launch_bounds__(NTHREADS)
void calc_kernel(const float* __restrict__ betas,
                 const float* __restrict__ lambdas,
                 const float* __restrict__ gammas,
                 float* __restrict__ out)
{
    __shared__ float4 s4[DIM];                              // 64 KB
    double* overlay = reinterpret_cast<double*>(s4);        // small scratch, time-multiplexed

    const int t = threadIdx.x;
    const int lane = t & 63;
    const int wave = t >> 6;                                // 16 waves

    // ---- Phase 1: per-thread totals over 4 contiguous j ----
    double v[4][4];
    double tot[4] = {0.0, 0.0, 0.0, 0.0};
    const int j0 = t * 4;
    #pragma unroll
    for (int i = 0; i < 4; ++i) {
        int j = j0 + i;
        float ga = gammas[j];
        float la = lambdas[j];
        double g  = (double)ga;
        double e0 = g;
        double e1 = g * (double)logf((float)(j + 1));
        double e2 = g * (double)logf(la);
        double e3 = g * (double)log1pf(-la);
        v[i][0] = e0; v[i][1] = e1; v[i][2] = e2; v[i][3] = e3;
        tot[0] += e0; tot[1] += e1; tot[2] += e2; tot[3] += e3;
    }

    // wave-level inclusive scan of per-thread totals (shfl, width 64)
    double incl[4];
    #pragma unroll
    for (int q = 0; q < 4; ++q) {
        double x = tot[q];
        #pragma unroll
        for (int off = 1; off < 64; off <<= 1) {
            double y = __shfl_up(x, off, 64);
            if (lane >= off) x += y;
        }
        incl[q] = x;
    }

    // wave totals -> LDS, exclusive-scan the 16 wave totals
    if (lane == 63) {
        #pragma unroll
        for (int q = 0; q < 4; ++q) overlay[q * 16 + wave] = incl[q];
    }
    __syncthreads();
    if (t < 4) {
        double run = 0.0;
        for (int w = 0; w < 16; ++w) {
            double vv = overlay[t * 16 + w];
            overlay[t * 16 + w] = run;   // exclusive wave base
            run += vv;
        }
    }
    __syncthreads();
    double base[4];
    #pragma unroll
    for (int q = 0; q < 4; ++q)
        base[q] = overlay[q * 16 + wave] + (incl[q] - tot[q]); // thread-exclusive base
    __syncthreads();   // everyone has read overlay; safe to overwrite s4

    // write inclusive prefixes, interleaved float4 per j
    {
        double run0 = base[0], run1 = base[1], run2 = base[2], run3 = base[3];
        #pragma unroll
        for (int i = 0; i < 4; ++i) {
            int j = j0 + i;
            run0 += v[i][0]; run1 += v[i][1]; run2 += v[i][2]; run3 += v[i][3];
            s4[j] = make_float4((float)run0, (float)run1, (float)run2, (float)run3);
        }
    }
    __syncthreads();

    // ---- Phase 2: per-beta gathers (coalesced beta loads, LDS b128 gather) ----
    double a_ixt = 0.0, a_nI = 0.0, a_lam = 0.0, a_lam1 = 0.0;
    #pragma unroll
    for (int r = 0; r < BATCH / NTHREADS; ++r) {
        int b = r * NTHREADS + t;
        float beta = betas[b];
        // replicate reference f32 op sequence exactly (floor boundary fidelity)
        float lamb = 1.0f - 1.0f / beta;
        float kf   = 1.0f / (1.0f - lamb) - 1.0f;
        int K = (int)floorf(kf);
        K = min(max(K, 1), DIM - 1);
        float4 p = s4[K - 1];                 // inclusive prefix at K-1 == sum_{j<K}
        double G = (double)p.x;
        a_ixt  += (double)logf((float)K) * G - (double)p.y;
        a_nI   += G;
        a_lam  += (double)p.z;
        a_lam1 += (double)p.w;
    }

    // ---- Phase 3: reduce + epilogue ----
    double r0 = a_ixt, r1 = a_nI, r2 = a_lam, r3 = a_lam1;
    #pragma unroll
    for (int off = 32; off > 0; off >>= 1) {
        r0 += __shfl_down(r0, off, 64);
        r1 += __shfl_down(r1, off, 64);
        r2 += __shfl_down(r2, off, 64);
        r3 += __shfl_down(r3, off, 64);
    }
    __syncthreads();   // phase-2 LDS reads done before overlay reuse
    if (lane == 0) {
        overlay[0 * 16 + wave] = r0;
        overlay[1 * 16 + wave] = r1;
        overlay[2 * 16 + wave] = r2;
        overlay[3 * 16 + wave] = r3;
    }
    __syncthreads();
    if (t == 0) {
        double ixt = 0.0, nI = 0.0, Sl = 0.0, Sl1 = 0.0;
        for (int w = 0; w < 16; ++w) {
            ixt += overlay[w];
            nI  += overlay[16 + w];
            Sl  += overlay[32 + w];
            Sl1 += overlay[48 + w];
        }
        double gm_term  = exp(Sl / nI);
        double gm_comp  = exp(Sl1 / nI);
        double exp_term = exp(2.0 * ixt / nI);
        double log_term = -nI * 0.5 * log(gm_comp + exp_term * gm_term);
        double ity = ixt + log_term;
        double rhs = 1.0 - ity;               // IXY = 1
        double lhs1 = 1.0 - ixt / 10.0;       // HX = 10
        if (lhs1 < 0.0) lhs1 = fabs(lhs1) * 20.0;
        double lhs = lhs1 * lhs1;             // C=1, ALPHA=2
        out[0] = (float)rhs;
        out[1] = (float)lhs;
    }
}

extern "C" void kernel_launch(void* const* d_in, const int* in_sizes, int n_in,
                              void* d_out, int out_size, void* d_ws, size_t ws_size,
                              hipStream_t stream) {
    const float* betas   = (const float*)d_in[0];
    const float* lambdas = (const float*)d_in[1];
    const float* gammas  = (const float*)d_in[2];
    float* out = (float*)d_out;
    calc_kernel<<<1, NTHREADS, 0, stream>>>(betas, lambdas, gammas, out);
}

// Round 2
// 13.651 us; speedup vs baseline: 1.4127x; 1.4127x over previous
//
#include <hip/hip_runtime.h>
#include <math.h>

#define DIM 4096
#define BATCH 8192
#define NT 1024
#define NWAVES (NT / 64)
#define RPT (BATCH / NT)   // betas per thread = 8

// Single-block fused kernel, all-f32 internal math (error budget ~2%, f32 scan
// error ~1e-4 relative -> 100x margin), f64 only in the thread-0 epilogue.
//
// Phase 0: load betas early, compute K + logK (hides HBM latency under phase 1)
// Phase 1: f32 inclusive prefix scan over j of 4 series -> LDS float4[DIM]
// Phase 2: per-beta LDS gather at K-1, f32 accumulate
// Phase 3: shfl reduce + f64 scalar epilogue -> out[0]=rhs, out[1]=lhs
__global__ __launch_bounds__(NT)
void calc_kernel(const float* __restrict__ betas,
                 const float* __restrict__ lambdas,
                 const float* __restrict__ gammas,
                 float* __restrict__ out)
{
    __shared__ float4 s4[DIM];          // 64 KB prefix table
    __shared__ float ovl[4 * NWAVES];   // wave totals -> exclusive bases
    __shared__ float red[4 * NWAVES];   // final reduction scratch

    const int t = threadIdx.x;
    const int lane = t & 63;
    const int wave = t >> 6;
    const int j0 = t * 4;

    // ---- issue all global loads up front ----
    float4 la4 = *reinterpret_cast<const float4*>(lambdas + j0);
    float4 ga4 = *reinterpret_cast<const float4*>(gammas + j0);
    float bet[RPT];
    #pragma unroll
    for (int r = 0; r < RPT; ++r) bet[r] = betas[r * NT + t];

    // ---- phase 0: K + logK per beta (exact f32 op sequence for floor fidelity) ----
    int   K[RPT];
    float lk[RPT];
    #pragma unroll
    for (int r = 0; r < RPT; ++r) {
        float beta = bet[r];
        float lamb = 1.0f - 1.0f / beta;
        float kf   = 1.0f / (1.0f - lamb) - 1.0f;
        int k = (int)floorf(kf);
        k = min(max(k, 1), DIM - 1);
        K[r]  = k;
        lk[r] = __logf((float)k);
    }

    // ---- phase 1: per-element 4-series values ----
    float las[4] = { la4.x, la4.y, la4.z, la4.w };
    float gas[4] = { ga4.x, ga4.y, ga4.z, ga4.w };
    float e[4][4];
    float tot0 = 0.f, tot1 = 0.f, tot2 = 0.f, tot3 = 0.f;
    #pragma unroll
    for (int i = 0; i < 4; ++i) {
        float g = gas[i];
        float l = las[i];
        float v0 = g;
        float v1 = g * __logf((float)(j0 + i + 1));
        float v2 = g * __logf(l);
        float v3 = g * __logf(1.0f - l);   // log1p(-l), l in (0.05,0.95): safe
        e[i][0] = v0; e[i][1] = v1; e[i][2] = v2; e[i][3] = v3;
        tot0 += v0; tot1 += v1; tot2 += v2; tot3 += v3;
    }

    // wave-level inclusive scan of per-thread totals (f32 shfl, width 64)
    float i0 = tot0, i1 = tot1, i2 = tot2, i3 = tot3;
    #pragma unroll
    for (int off = 1; off < 64; off <<= 1) {
        float y0 = __shfl_up(i0, off, 64);
        float y1 = __shfl_up(i1, off, 64);
        float y2 = __shfl_up(i2, off, 64);
        float y3 = __shfl_up(i3, off, 64);
        if (lane >= off) { i0 += y0; i1 += y1; i2 += y2; i3 += y3; }
    }
    if (lane == 63) {
        ovl[0 * NWAVES + wave] = i0;
        ovl[1 * NWAVES + wave] = i1;
        ovl[2 * NWAVES + wave] = i2;
        ovl[3 * NWAVES + wave] = i3;
    }
    __syncthreads();

    // wave 0: 64 lanes = 4 series x 16 waves; segmented exclusive scan, width 16
    if (wave == 0) {
        float x = ovl[lane];
        float inc = x;
        #pragma unroll
        for (int off = 1; off < 16; off <<= 1) {
            float y = __shfl_up(inc, off, 16);
            if ((lane & 15) >= off) inc += y;
        }
        ovl[lane] = inc - x;   // exclusive wave base
    }
    __syncthreads();

    // thread base = wave base + (wave-inclusive - own total); write prefixes
    float b0 = ovl[0 * NWAVES + wave] + (i0 - tot0);
    float b1 = ovl[1 * NWAVES + wave] + (i1 - tot1);
    float b2 = ovl[2 * NWAVES + wave] + (i2 - tot2);
    float b3 = ovl[3 * NWAVES + wave] + (i3 - tot3);
    #pragma unroll
    for (int i = 0; i < 4; ++i) {
        b0 += e[i][0]; b1 += e[i][1]; b2 += e[i][2]; b3 += e[i][3];
        s4[j0 + i] = make_float4(b0, b1, b2, b3);
    }
    __syncthreads();

    // ---- phase 2: per-beta gathers ----
    float a0 = 0.f, a1 = 0.f, a2 = 0.f, a3 = 0.f;
    #pragma unroll
    for (int r = 0; r < RPT; ++r) {
        float4 p = s4[K[r] - 1];           // inclusive prefix at K-1 == sum_{j<K}
        a0 += lk[r] * p.x - p.y;           // ixt contribution
        a1 += p.x;                         // n_I
        a2 += p.z;                         // sum mg*log(lam) (unnormalized)
        a3 += p.w;                         // sum mg*log1p(-lam) (unnormalized)
    }

    // ---- phase 3: reduce + epilogue ----
    #pragma unroll
    for (int off = 32; off > 0; off >>= 1) {
        a0 += __shfl_down(a0, off, 64);
        a1 += __shfl_down(a1, off, 64);
        a2 += __shfl_down(a2, off, 64);
        a3 += __shfl_down(a3, off, 64);
    }
    if (lane == 0) {
        red[0 * NWAVES + wave] = a0;
        red[1 * NWAVES + wave] = a1;
        red[2 * NWAVES + wave] = a2;
        red[3 * NWAVES + wave] = a3;
    }
    __syncthreads();
    if (t == 0) {
        double ixt = 0.0, nI = 0.0, Sl = 0.0, Sl1 = 0.0;
        for (int w = 0; w < NWAVES; ++w) {
            ixt += red[w];
            nI  += red[NWAVES + w];
            Sl  += red[2 * NWAVES + w];
            Sl1 += red[3 * NWAVES + w];
        }
        double gm_term  = exp(Sl / nI);
        double gm_comp  = exp(Sl1 / nI);
        double exp_term = exp(2.0 * ixt / nI);
        double log_term = -nI * 0.5 * log(gm_comp + exp_term * gm_term);
        double ity = ixt + log_term;
        double rhs = 1.0 - ity;               // IXY = 1
        double l1  = 1.0 - ixt / 10.0;        // HX = 10
        if (l1 < 0.0) l1 = fabs(l1) * 20.0;
        out[0] = (float)rhs;
        out[1] = (float)(l1 * l1);            // C=1, ALPHA=2
    }
}

extern "C" void kernel_launch(void* const* d_in, const int* in_sizes, int n_in,
                              void* d_out, int out_size, void* d_ws, size_t ws_size,
                              hipStream_t stream) {
    const float* betas   = (const float*)d_in[0];
    const float* lambdas = (const float*)d_in[1];
    const float* gammas  = (const float*)d_in[2];
    calc_kernel<<<1, NT, 0, stream>>>(betas, lambdas, gammas, (float*)d_out);
}

// Round 3
// 12.704 us; speedup vs baseline: 1.5180x; 1.0745x over previous
//
#include <hip/hip_runtime.h>
#include <math.h>

#define DIM 4096
#define BATCH 8192
#define NT 1024
#define NWAVES (NT / 64)
#define RPT (BATCH / NT)   // betas per thread = 8

// Single-block fused kernel, all-f32 (error budget ~3.3e5 on lhs -> dixt
// budget ~20; f32 end-to-end error ~1e-3). Hardware transcendentals only.
//
// Phase 0: float4 loads of lambdas/gammas/betas; K + logK per beta
// Phase 1: f32 inclusive prefix scan of 4 series -> LDS float4[DIM]
//          (wave shfl scan; cross-wave bases by direct LDS summation - 1 barrier)
// Phase 2: per-beta LDS gather at K-1, f32 accumulate
// Phase 3: per-wave shfl reduce -> LDS float4; thread-0 f32 epilogue
__global__ __launch_bounds__(NT)
void calc_kernel(const float* __restrict__ betas,
                 const float* __restrict__ lambdas,
                 const float* __restrict__ gammas,
                 float* __restrict__ out)
{
    __shared__ float4 s4[DIM];        // 64 KB prefix table
    __shared__ float4 ovl4[NWAVES];   // per-wave totals of the 4 series
    __shared__ float4 red4[NWAVES];   // per-wave phase-2 partial sums

    const int t = threadIdx.x;
    const int lane = t & 63;
    const int wave = t >> 6;
    const int j0 = t * 4;

    // ---- issue all global loads up front (hide latency under phase-1 math) ----
    const float4 la4 = *reinterpret_cast<const float4*>(lambdas + j0);
    const float4 ga4 = *reinterpret_cast<const float4*>(gammas + j0);
    const float4* b4p = reinterpret_cast<const float4*>(betas);
    float4 bv[RPT / 4];
    #pragma unroll
    for (int r = 0; r < RPT / 4; ++r) bv[r] = b4p[r * NT + t];

    // ---- K + logK per beta (exact f32 op sequence for floor fidelity) ----
    float bet[RPT] = { bv[0].x, bv[0].y, bv[0].z, bv[0].w,
                       bv[1].x, bv[1].y, bv[1].z, bv[1].w };
    int   K[RPT];
    float lk[RPT];
    #pragma unroll
    for (int r = 0; r < RPT; ++r) {
        float beta = bet[r];
        float lamb = 1.0f - 1.0f / beta;     // IEEE divides (no fast-math):
        float kf   = 1.0f / (1.0f - lamb) - 1.0f;  // must match numpy floor edges
        int k = (int)floorf(kf);
        k = min(max(k, 1), DIM - 1);
        K[r]  = k;
        lk[r] = __logf((float)k);
    }

    // ---- phase 1: per-element series values ----
    float las[4] = { la4.x, la4.y, la4.z, la4.w };
    float gas[4] = { ga4.x, ga4.y, ga4.z, ga4.w };
    float e[4][4];
    float tot0 = 0.f, tot1 = 0.f, tot2 = 0.f, tot3 = 0.f;
    #pragma unroll
    for (int i = 0; i < 4; ++i) {
        float g = gas[i];
        float l = las[i];
        float v0 = g;
        float v1 = g * __logf((float)(j0 + i + 1));
        float v2 = g * __logf(l);
        float v3 = g * __logf(1.0f - l);     // l in (0.05,0.95): log1p safe as log
        e[i][0] = v0; e[i][1] = v1; e[i][2] = v2; e[i][3] = v3;
        tot0 += v0; tot1 += v1; tot2 += v2; tot3 += v3;
    }

    // wave-level inclusive scan of per-thread totals (f32 shfl, width 64)
    float i0 = tot0, i1 = tot1, i2 = tot2, i3 = tot3;
    #pragma unroll
    for (int off = 1; off < 64; off <<= 1) {
        float y0 = __shfl_up(i0, off, 64);
        float y1 = __shfl_up(i1, off, 64);
        float y2 = __shfl_up(i2, off, 64);
        float y3 = __shfl_up(i3, off, 64);
        if (lane >= off) { i0 += y0; i1 += y1; i2 += y2; i3 += y3; }
    }
    if (lane == 63) ovl4[wave] = make_float4(i0, i1, i2, i3);
    __syncthreads();

    // cross-wave base: directly sum preceding wave totals (broadcast b128 reads)
    float b0 = i0 - tot0, b1 = i1 - tot1, b2 = i2 - tot2, b3 = i3 - tot3;
    for (int w = 0; w < wave; ++w) {
        float4 o = ovl4[w];
        b0 += o.x; b1 += o.y; b2 += o.z; b3 += o.w;
    }
    #pragma unroll
    for (int i = 0; i < 4; ++i) {
        b0 += e[i][0]; b1 += e[i][1]; b2 += e[i][2]; b3 += e[i][3];
        s4[j0 + i] = make_float4(b0, b1, b2, b3);
    }
    __syncthreads();

    // ---- phase 2: per-beta gathers ----
    float a0 = 0.f, a1 = 0.f, a2 = 0.f, a3 = 0.f;
    #pragma unroll
    for (int r = 0; r < RPT; ++r) {
        float4 p = s4[K[r] - 1];       // inclusive prefix at K-1 == sum_{j<K}
        a0 += lk[r] * p.x - p.y;       // ixt contribution
        a1 += p.x;                     // n_I
        a2 += p.z;                     // sum g*log(lam) over mask
        a3 += p.w;                     // sum g*log1p(-lam) over mask
    }

    // ---- phase 3: per-wave reduce, then thread-0 f32 epilogue ----
    #pragma unroll
    for (int off = 32; off > 0; off >>= 1) {
        a0 += __shfl_down(a0, off, 64);
        a1 += __shfl_down(a1, off, 64);
        a2 += __shfl_down(a2, off, 64);
        a3 += __shfl_down(a3, off, 64);
    }
    if (lane == 0) red4[wave] = make_float4(a0, a1, a2, a3);
    __syncthreads();
    if (t == 0) {
        float ixt = 0.f, nI = 0.f, Sl = 0.f, Sl1 = 0.f;
        #pragma unroll
        for (int w = 0; w < NWAVES; ++w) {
            float4 rv = red4[w];
            ixt += rv.x; nI += rv.y; Sl += rv.z; Sl1 += rv.w;
        }
        float inv_nI = 1.0f / nI;
        float gm_term  = __expf(Sl * inv_nI);     // normalized in exponent
        float gm_comp  = __expf(Sl1 * inv_nI);
        float exp_term = __expf(2.0f * ixt * inv_nI);
        float log_term = -nI * 0.5f * __logf(gm_comp + exp_term * gm_term);
        float ity = ixt + log_term;
        float rhs = 1.0f - ity;                   // IXY = 1
        float l1  = 1.0f - ixt * 0.1f;            // HX = 10
        if (l1 < 0.0f) l1 = fabsf(l1) * 20.0f;
        out[0] = rhs;
        out[1] = l1 * l1;                         // C=1, ALPHA=2
    }
}

extern "C" void kernel_launch(void* const* d_in, const int* in_sizes, int n_in,
                              void* d_out, int out_size, void* d_ws, size_t ws_size,
                              hipStream_t stream) {
    const float* betas   = (const float*)d_in[0];
    const float* lambdas = (const float*)d_in[1];
    const float* gammas  = (const float*)d_in[2];
    calc_kernel<<<1, NT, 0, stream>>>(betas, lambdas, gammas, (float*)d_out);
}